// Round 1
// baseline (1239.425 us; speedup 1.0000x reference)
//
#include <hip/hip_runtime.h>

#define S 2048
#define E 1152
#define H 16
#define D 72
#define DH 36
#define NSEG 4

#define BM 64
#define BN 64
#define BK 16

// C[M,N] = A[M,K] @ W[N,K]^T + bias[N]   (all fp32, row-major)
__global__ __launch_bounds__(256)
void gemm_bt_bias_f32(const float* __restrict__ A, const float* __restrict__ W,
                      const float* __restrict__ bias, float* __restrict__ C,
                      int M, int N, int K)
{
    __shared__ float As[BK][BM + 4];
    __shared__ float Ws[BK][BN + 4];
    const int tid = threadIdx.x;
    const int tx = tid & 15;        // col group
    const int ty = tid >> 4;        // row group
    const int bm = blockIdx.y * BM;
    const int bn = blockIdx.x * BN;
    const int lrow = tid >> 2;          // 0..63
    const int lk   = (tid & 3) * 4;     // 0,4,8,12

    float acc[4][4];
#pragma unroll
    for (int i = 0; i < 4; ++i)
#pragma unroll
        for (int j = 0; j < 4; ++j) acc[i][j] = 0.f;

    for (int k0 = 0; k0 < K; k0 += BK) {
        float4 av = *(const float4*)&A[(size_t)(bm + lrow) * K + k0 + lk];
        float4 wv = *(const float4*)&W[(size_t)(bn + lrow) * K + k0 + lk];
        As[lk + 0][lrow] = av.x; As[lk + 1][lrow] = av.y;
        As[lk + 2][lrow] = av.z; As[lk + 3][lrow] = av.w;
        Ws[lk + 0][lrow] = wv.x; Ws[lk + 1][lrow] = wv.y;
        Ws[lk + 2][lrow] = wv.z; Ws[lk + 3][lrow] = wv.w;
        __syncthreads();
#pragma unroll
        for (int kk = 0; kk < BK; ++kk) {
            float4 a = *(const float4*)&As[kk][ty * 4];
            float4 b = *(const float4*)&Ws[kk][tx * 4];
            float ar[4] = {a.x, a.y, a.z, a.w};
            float br[4] = {b.x, b.y, b.z, b.w};
#pragma unroll
            for (int i = 0; i < 4; ++i)
#pragma unroll
                for (int j = 0; j < 4; ++j)
                    acc[i][j] += ar[i] * br[j];
        }
        __syncthreads();
    }
#pragma unroll
    for (int i = 0; i < 4; ++i) {
        int r = bm + ty * 4 + i;
#pragma unroll
        for (int j = 0; j < 4; ++j) {
            int c = bn + tx * 4 + j;
            C[(size_t)r * N + c] = acc[i][j] + bias[c];
        }
    }
}

// RoPE applied in-place to q and k. One thread per (s, h, d<36), handles both halves.
__global__ __launch_bounds__(256)
void rope_f32(float* __restrict__ q, float* __restrict__ k,
              const float* __restrict__ cosp, const float* __restrict__ sinp)
{
    int idx = blockIdx.x * blockDim.x + threadIdx.x;
    if (idx >= S * H * DH) return;
    int d = idx % DH;
    int h = (idx / DH) % H;
    int s = idx / (DH * H);
    float c0 = cosp[s * D + d],      s0 = sinp[s * D + d];
    float c1 = cosp[s * D + d + DH], s1 = sinp[s * D + d + DH];

    float* qb = q + (size_t)s * E + h * D;
    float x0 = qb[d], x1 = qb[d + DH];
    qb[d]      = x0 * c0 - x1 * s0;   // x*cos + rotate_half(x)*sin, first half: rh = -x[d+36]
    qb[d + DH] = x1 * c1 + x0 * s1;

    float* kb = k + (size_t)s * E + h * D;
    float y0 = kb[d], y1 = kb[d + DH];
    kb[d]      = y0 * c0 - y1 * s0;
    kb[d + DH] = y1 * c1 + y0 * s1;
}

// Block-diagonal attention. One block = (32 q rows, 1 head). Two-pass softmax,
// scores staged in LDS. Segment bounds read from cu_seqlens (assumed tile-aligned).
__global__ __launch_bounds__(256)
void attn_seg_f32(const float* __restrict__ q, const float* __restrict__ k,
                  const float* __restrict__ v, float* __restrict__ o,
                  const int* __restrict__ cu, int nseg)
{
    __shared__ float qs[32][77];
    __shared__ float ks[32][77];   // reused for V in second pass
    __shared__ float ss[32][512];

    const int h   = blockIdx.y;
    const int q0  = blockIdx.x * 32;
    const int tid = threadIdx.x;

    int kstart = 0, kend = S;
    for (int i = 0; i < nseg; ++i) {
        int a = cu[i], b = cu[i + 1];
        if (q0 >= a && q0 < b) { kstart = a; kend = b; }
    }
    const int L = kend - kstart;
    const float scale = rsqrtf((float)D);

    // load q tile (pre-scaled)
    for (int idx = tid; idx < 32 * D; idx += 256) {
        int r = idx / D, d = idx - r * D;
        qs[r][d] = q[(size_t)(q0 + r) * E + h * D + d] * scale;
    }
    __syncthreads();

    // pass 1: scores
    for (int kc = 0; kc < L; kc += 32) {
        for (int idx = tid; idx < 32 * D; idx += 256) {
            int r = idx / D, d = idx - r * D;
            ks[r][d] = k[(size_t)(kstart + kc + r) * E + h * D + d];
        }
        __syncthreads();
#pragma unroll
        for (int t = 0; t < 4; ++t) {
            int idx = tid + t * 256;
            int qi = idx & 31, kj = idx >> 5;
            float acc = 0.f;
#pragma unroll 8
            for (int d = 0; d < D; ++d) acc += qs[qi][d] * ks[kj][d];
            ss[qi][kc + kj] = acc;
        }
        __syncthreads();
    }

    // softmax: 8 lanes per row
    {
        int row = tid >> 3, sub = tid & 7;
        float m = -3.4e38f;
        for (int j = sub; j < L; j += 8) m = fmaxf(m, ss[row][j]);
#pragma unroll
        for (int sft = 4; sft >= 1; sft >>= 1) m = fmaxf(m, __shfl_xor(m, sft, 8));
        float sum = 0.f;
        for (int j = sub; j < L; j += 8) {
            float e = __expf(ss[row][j] - m);
            ss[row][j] = e;
            sum += e;
        }
#pragma unroll
        for (int sft = 4; sft >= 1; sft >>= 1) sum += __shfl_xor(sum, sft, 8);
        float inv = 1.0f / sum;
        for (int j = sub; j < L; j += 8) ss[row][j] *= inv;
    }
    __syncthreads();

    // pass 2: O = P @ V   (2304 outputs, 9 per thread)
    float acc[9];
#pragma unroll
    for (int i = 0; i < 9; ++i) acc[i] = 0.f;

    for (int kc = 0; kc < L; kc += 32) {
        for (int idx = tid; idx < 32 * D; idx += 256) {
            int r = idx / D, d = idx - r * D;
            ks[r][d] = v[(size_t)(kstart + kc + r) * E + h * D + d];
        }
        __syncthreads();
#pragma unroll
        for (int i = 0; i < 9; ++i) {
            int idx = tid + i * 256;
            int qi = idx / D, d = idx - qi * D;
            float a = 0.f;
#pragma unroll 8
            for (int j = 0; j < 32; ++j) a += ss[qi][kc + j] * ks[j][d];
            acc[i] += a;
        }
        __syncthreads();
    }

#pragma unroll
    for (int i = 0; i < 9; ++i) {
        int idx = tid + i * 256;
        int qi = idx / D, d = idx - qi * D;
        o[(size_t)(q0 + qi) * E + h * D + d] = acc[i];
    }
}

extern "C" void kernel_launch(void* const* d_in, const int* in_sizes, int n_in,
                              void* d_out, int out_size, void* d_ws, size_t ws_size,
                              hipStream_t stream)
{
    const float* hs   = (const float*)d_in[0];
    const float* q_w  = (const float*)d_in[1];
    const float* q_b  = (const float*)d_in[2];
    const float* k_w  = (const float*)d_in[3];
    const float* k_b  = (const float*)d_in[4];
    const float* v_w  = (const float*)d_in[5];
    const float* v_b  = (const float*)d_in[6];
    const float* o_w  = (const float*)d_in[7];
    const float* o_b  = (const float*)d_in[8];
    const float* cosp = (const float*)d_in[9];
    const float* sinp = (const float*)d_in[10];
    const int*   cu   = (const int*)d_in[11];
    float* out = (float*)d_out;

    float* q    = (float*)d_ws;
    float* k    = q + (size_t)S * E;
    float* v    = k + (size_t)S * E;
    float* attn = v + (size_t)S * E;

    dim3 gg(E / BN, S / BM);  // (18, 32)
    gemm_bt_bias_f32<<<gg, 256, 0, stream>>>(hs, q_w, q_b, q, S, E, E);
    gemm_bt_bias_f32<<<gg, 256, 0, stream>>>(hs, k_w, k_b, k, S, E, E);
    gemm_bt_bias_f32<<<gg, 256, 0, stream>>>(hs, v_w, v_b, v, S, E, E);

    int nt = S * H * DH;
    rope_f32<<<(nt + 255) / 256, 256, 0, stream>>>(q, k, cosp, sinp);

    dim3 ga(S / 32, H);       // (64, 16)
    attn_seg_f32<<<ga, 256, 0, stream>>>(q, k, v, attn, cu, NSEG);

    gemm_bt_bias_f32<<<gg, 256, 0, stream>>>(attn, o_w, o_b, out, S, E, E);
}

// Round 2
// 280.451 us; speedup vs baseline: 4.4194x; 4.4194x over previous
//
#include <hip/hip_runtime.h>

#define S 2048
#define E 1152
#define H 16
#define NSEG 4

typedef unsigned short u16;
typedef short bf16x8 __attribute__((ext_vector_type(8)));
typedef float f32x4 __attribute__((ext_vector_type(4)));

#define MFMA __builtin_amdgcn_mfma_f32_16x16x32_bf16

__device__ __forceinline__ u16 f2bf(float x) {
    unsigned u = __float_as_uint(x);
    u += 0x7fffu + ((u >> 16) & 1u);
    return (u16)(u >> 16);
}
__device__ __forceinline__ float bf2f(u16 h) {
    return __uint_as_float(((unsigned)h) << 16);
}
__device__ __forceinline__ bf16x8 ldb8(const u16* p) {
    return *(const bf16x8*)p;
}

// ---------------- fp32 -> bf16 conversion of hs + weights ----------------
// ranges: hs (hi only), wq/wk/wv (hi only), wo (hi+lo)
__global__ __launch_bounds__(256)
void convert_inputs(const float* __restrict__ hs, const float* __restrict__ wq,
                    const float* __restrict__ wk, const float* __restrict__ wv,
                    const float* __restrict__ wo,
                    u16* __restrict__ hs_h, u16* __restrict__ wq_h,
                    u16* __restrict__ wk_h, u16* __restrict__ wv_h,
                    u16* __restrict__ wo_h, u16* __restrict__ wo_l)
{
    const size_t NH = (size_t)S * E, NW = (size_t)E * E;
    size_t i = ((size_t)blockIdx.x * 256 + threadIdx.x) * 4;
    const float* src; u16* dst; u16* dst2 = nullptr; size_t off;
    if      (i < NH)          { src = hs; dst = hs_h; off = i; }
    else if (i < NH + NW)     { src = wq; dst = wq_h; off = i - NH; }
    else if (i < NH + 2*NW)   { src = wk; dst = wk_h; off = i - NH - 2*NW + NW; }
    else if (i < NH + 3*NW)   { src = wv; dst = wv_h; off = i - NH - 2*NW; }
    else if (i < NH + 4*NW)   { src = wo; dst = wo_h; dst2 = wo_l; off = i - NH - 3*NW; }
    else return;
    float4 v = *(const float4*)(src + off);
    ushort4 hv;
    hv.x = f2bf(v.x); hv.y = f2bf(v.y); hv.z = f2bf(v.z); hv.w = f2bf(v.w);
    *(ushort4*)(dst + off) = hv;
    if (dst2) {
        ushort4 lv;
        lv.x = f2bf(v.x - bf2f(hv.x)); lv.y = f2bf(v.y - bf2f(hv.y));
        lv.z = f2bf(v.z - bf2f(hv.z)); lv.w = f2bf(v.w - bf2f(hv.w));
        *(ushort4*)(dst2 + off) = lv;
    }
}

// ---------------- QKV projection: C = hs @ W^T + b (bf16 MFMA, no LDS) -----
// grid (E/64, S/64, 3); block 256 = 4 waves (2x2), wave tile 32x32.
// z=0 -> q fp32, z=1 -> k fp32, z=2 -> v written transposed bf16 into vt[h][d][s]
__global__ __launch_bounds__(256)
void gemm_qkv(const u16* __restrict__ hs,
              const u16* __restrict__ wq, const u16* __restrict__ wk, const u16* __restrict__ wv,
              const float* __restrict__ qb, const float* __restrict__ kb, const float* __restrict__ vb,
              float* __restrict__ qo, float* __restrict__ ko, u16* __restrict__ vt)
{
    const int z = blockIdx.z;
    const u16* W = (z == 0) ? wq : (z == 1) ? wk : wv;
    const float* bias = (z == 0) ? qb : (z == 1) ? kb : vb;
    const int l = threadIdx.x & 63, w = threadIdx.x >> 6;
    const int wr = w >> 1, wc = w & 1;
    const size_t arow = blockIdx.y * 64 + wr * 32 + (l & 15);
    const size_t brow = blockIdx.x * 64 + wc * 32 + (l & 15);
    const int koff = (l >> 4) * 8;
    const u16* ap0 = hs + arow * E + koff;
    const u16* ap1 = ap0 + (size_t)16 * E;
    const u16* bp0 = W + brow * E + koff;
    const u16* bp1 = bp0 + (size_t)16 * E;

    f32x4 acc[2][2] = {};
#pragma unroll
    for (int ks = 0; ks < E / 32; ++ks) {
        bf16x8 a0 = ldb8(ap0 + ks * 32);
        bf16x8 a1 = ldb8(ap1 + ks * 32);
        bf16x8 b0 = ldb8(bp0 + ks * 32);
        bf16x8 b1 = ldb8(bp1 + ks * 32);
        acc[0][0] = MFMA(a0, b0, acc[0][0], 0, 0, 0);
        acc[0][1] = MFMA(a0, b1, acc[0][1], 0, 0, 0);
        acc[1][0] = MFMA(a1, b0, acc[1][0], 0, 0, 0);
        acc[1][1] = MFMA(a1, b1, acc[1][1], 0, 0, 0);
    }
    float* outp = (z == 0) ? qo : ko;
#pragma unroll
    for (int mi = 0; mi < 2; ++mi)
#pragma unroll
        for (int ni = 0; ni < 2; ++ni)
#pragma unroll
            for (int r = 0; r < 4; ++r) {
                int rr = blockIdx.y * 64 + wr * 32 + mi * 16 + (l >> 4) * 4 + r;
                int cc = blockIdx.x * 64 + wc * 32 + ni * 16 + (l & 15);
                float val = acc[mi][ni][r] + bias[cc];
                if (z < 2) {
                    outp[(size_t)rr * E + cc] = val;
                } else {
                    int h = cc / 72, d = cc - h * 72;
                    vt[((size_t)h * 80 + d) * S + rr] = f2bf(val);
                }
            }
}

// ---------------- RoPE (fp32) + pack q,k to padded bf16 + vt pad zeros -----
__global__ __launch_bounds__(256)
void rope_convert(const float* __restrict__ qf, const float* __restrict__ kf,
                  const float* __restrict__ cosp, const float* __restrict__ sinp,
                  u16* __restrict__ qbf, u16* __restrict__ kbf, u16* __restrict__ vt)
{
    int idx = blockIdx.x * 256 + threadIdx.x;
    if (idx >= S * H * 36) return;
    int d = idx % 36;
    int h = (idx / 36) % H;
    int s = idx / (36 * H);
    float c = cosp[s * 72 + d], sn = sinp[s * 72 + d];
    size_t base = (size_t)s * E + h * 72;
    float q0 = qf[base + d], q1 = qf[base + d + 36];
    float k0 = kf[base + d], k1 = kf[base + d + 36];
    const float scale = 0.1178511301977579f;  // 72^-0.5
    float rq0 = (q0 * c - q1 * sn) * scale;
    float rq1 = (q1 * c + q0 * sn) * scale;
    float rk0 = k0 * c - k1 * sn;
    float rk1 = k1 * c + k0 * sn;
    size_t qkbase = ((size_t)h * S + s) * 96;
    qbf[qkbase + d] = f2bf(rq0); qbf[qkbase + d + 36] = f2bf(rq1);
    kbf[qkbase + d] = f2bf(rk0); kbf[qkbase + d + 36] = f2bf(rk1);
    if (d < 24) { qbf[qkbase + 72 + d] = 0; kbf[qkbase + 72 + d] = 0; }
    if (d < 8)  { vt[((size_t)h * 80 + 72 + d) * S + s] = 0; }
}

// ---------------- flash attention, bf16 MFMA, barrier-free ----------------
// grid (S/64, H); block 256 = 4 waves; wave owns 16 q rows; kv chunks of 64.
__global__ __launch_bounds__(256)
void attn_mfma(const u16* __restrict__ qbf, const u16* __restrict__ kbf,
               const u16* __restrict__ vt, u16* __restrict__ ah, u16* __restrict__ al,
               const int* __restrict__ cu)
{
    __shared__ u16 p_lds[4][16][72] __attribute__((aligned(16)));
    const int h = blockIdx.y;
    const int q0 = blockIdx.x * 64;
    const int l = threadIdx.x & 63, w = threadIdx.x >> 6;

    int kstart = 0, kend = S;
#pragma unroll
    for (int i = 0; i < NSEG; ++i) {
        int a = cu[i], b = cu[i + 1];
        if (q0 >= a && q0 < b) { kstart = a; kend = b; }
    }

    const int koff = (l >> 4) * 8;
    const int qrow = q0 + w * 16 + (l & 15);
    bf16x8 qfr[3];
#pragma unroll
    for (int ks = 0; ks < 3; ++ks)
        qfr[ks] = ldb8(qbf + ((size_t)h * S + qrow) * 96 + ks * 32 + koff);

    f32x4 oacc[5] = {};
    float m[4], lsum[4];
#pragma unroll
    for (int r = 0; r < 4; ++r) { m[r] = -3.0e38f; lsum[r] = 0.f; }

    for (int kv0 = kstart; kv0 < kend; kv0 += 64) {
        // scores: S[16 x 64]
        f32x4 sc[4] = {};
#pragma unroll
        for (int nt = 0; nt < 4; ++nt) {
            const u16* kp = kbf + ((size_t)h * S + kv0 + nt * 16 + (l & 15)) * 96 + koff;
#pragma unroll
            for (int ks = 0; ks < 3; ++ks) {
                bf16x8 kfr = ldb8(kp + ks * 32);
                sc[nt] = MFMA(qfr[ks], kfr, sc[nt], 0, 0, 0);
            }
        }
        // online softmax update
        float mn[4], alpha[4];
#pragma unroll
        for (int r = 0; r < 4; ++r) {
            float mx = fmaxf(fmaxf(sc[0][r], sc[1][r]), fmaxf(sc[2][r], sc[3][r]));
            mx = fmaxf(mx, __shfl_xor(mx, 1));
            mx = fmaxf(mx, __shfl_xor(mx, 2));
            mx = fmaxf(mx, __shfl_xor(mx, 4));
            mx = fmaxf(mx, __shfl_xor(mx, 8));
            mn[r] = fmaxf(m[r], mx);
            alpha[r] = __expf(m[r] - mn[r]);
            m[r] = mn[r];
        }
        float rs[4] = {0.f, 0.f, 0.f, 0.f};
#pragma unroll
        for (int nt = 0; nt < 4; ++nt)
#pragma unroll
            for (int r = 0; r < 4; ++r) {
                float p = __expf(sc[nt][r] - mn[r]);
                rs[r] += p;
                p_lds[w][(l >> 4) * 4 + r][(l & 15) + nt * 16] = f2bf(p);
            }
#pragma unroll
        for (int r = 0; r < 4; ++r) {
            float t = rs[r];
            t += __shfl_xor(t, 1);
            t += __shfl_xor(t, 2);
            t += __shfl_xor(t, 4);
            t += __shfl_xor(t, 8);
            lsum[r] = lsum[r] * alpha[r] + t;
        }
#pragma unroll
        for (int nt = 0; nt < 5; ++nt)
#pragma unroll
            for (int r = 0; r < 4; ++r) oacc[nt][r] *= alpha[r];
        // PV
#pragma unroll
        for (int ks = 0; ks < 2; ++ks) {
            bf16x8 pf = ldb8(&p_lds[w][l & 15][ks * 32 + koff]);
#pragma unroll
            for (int nt = 0; nt < 5; ++nt) {
                bf16x8 vf = ldb8(vt + ((size_t)h * 80 + nt * 16 + (l & 15)) * S + kv0 + ks * 32 + koff);
                oacc[nt] = MFMA(pf, vf, oacc[nt], 0, 0, 0);
            }
        }
    }
    // epilogue: O /= l, write hi/lo bf16
#pragma unroll
    for (int r = 0; r < 4; ++r) {
        float inv = 1.0f / lsum[r];
        int srow = q0 + w * 16 + (l >> 4) * 4 + r;
#pragma unroll
        for (int nt = 0; nt < 5; ++nt) {
            int d = nt * 16 + (l & 15);
            if (d < 72) {
                float val = oacc[nt][r] * inv;
                u16 hi = f2bf(val);
                u16 lo = f2bf(val - bf2f(hi));
                ah[(size_t)srow * E + h * 72 + d] = hi;
                al[(size_t)srow * E + h * 72 + d] = lo;
            }
        }
    }
}

// ---------------- O projection: split-bf16 GEMM (hi/lo both sides) --------
__global__ __launch_bounds__(256)
void gemm_o(const u16* __restrict__ ah, const u16* __restrict__ al,
            const u16* __restrict__ wh, const u16* __restrict__ wl,
            const float* __restrict__ bias, float* __restrict__ out)
{
    const int l = threadIdx.x & 63, w = threadIdx.x >> 6;
    const int wr = w >> 1, wc = w & 1;
    const size_t arow = blockIdx.y * 64 + wr * 32 + (l & 15);
    const size_t brow = blockIdx.x * 64 + wc * 32 + (l & 15);
    const int koff = (l >> 4) * 8;
    const u16* ah0 = ah + arow * E + koff; const u16* ah1 = ah0 + (size_t)16 * E;
    const u16* al0 = al + arow * E + koff; const u16* al1 = al0 + (size_t)16 * E;
    const u16* bh0 = wh + brow * E + koff; const u16* bh1 = bh0 + (size_t)16 * E;
    const u16* bl0 = wl + brow * E + koff; const u16* bl1 = bl0 + (size_t)16 * E;

    f32x4 acc[2][2] = {};
#pragma unroll
    for (int ks = 0; ks < E / 32; ++ks) {
        bf16x8 aH[2] = { ldb8(ah0 + ks * 32), ldb8(ah1 + ks * 32) };
        bf16x8 aL[2] = { ldb8(al0 + ks * 32), ldb8(al1 + ks * 32) };
        bf16x8 bH[2] = { ldb8(bh0 + ks * 32), ldb8(bh1 + ks * 32) };
        bf16x8 bL[2] = { ldb8(bl0 + ks * 32), ldb8(bl1 + ks * 32) };
#pragma unroll
        for (int mi = 0; mi < 2; ++mi)
#pragma unroll
            for (int ni = 0; ni < 2; ++ni) {
                acc[mi][ni] = MFMA(aH[mi], bH[ni], acc[mi][ni], 0, 0, 0);
                acc[mi][ni] = MFMA(aH[mi], bL[ni], acc[mi][ni], 0, 0, 0);
                acc[mi][ni] = MFMA(aL[mi], bH[ni], acc[mi][ni], 0, 0, 0);
            }
    }
#pragma unroll
    for (int mi = 0; mi < 2; ++mi)
#pragma unroll
        for (int ni = 0; ni < 2; ++ni)
#pragma unroll
            for (int r = 0; r < 4; ++r) {
                int rr = blockIdx.y * 64 + wr * 32 + mi * 16 + (l >> 4) * 4 + r;
                int cc = blockIdx.x * 64 + wc * 32 + ni * 16 + (l & 15);
                out[(size_t)rr * E + cc] = acc[mi][ni][r] + bias[cc];
            }
}

extern "C" void kernel_launch(void* const* d_in, const int* in_sizes, int n_in,
                              void* d_out, int out_size, void* d_ws, size_t ws_size,
                              hipStream_t stream)
{
    const float* hs   = (const float*)d_in[0];
    const float* q_w  = (const float*)d_in[1];
    const float* q_b  = (const float*)d_in[2];
    const float* k_w  = (const float*)d_in[3];
    const float* k_b  = (const float*)d_in[4];
    const float* v_w  = (const float*)d_in[5];
    const float* v_b  = (const float*)d_in[6];
    const float* o_w  = (const float*)d_in[7];
    const float* o_b  = (const float*)d_in[8];
    const float* cosp = (const float*)d_in[9];
    const float* sinp = (const float*)d_in[10];
    const int*   cu   = (const int*)d_in[11];
    float* out = (float*)d_out;

    char* p = (char*)d_ws;
    u16* hs_h = (u16*)p; p += (size_t)S * E * 2;
    u16* wq_h = (u16*)p; p += (size_t)E * E * 2;
    u16* wk_h = (u16*)p; p += (size_t)E * E * 2;
    u16* wv_h = (u16*)p; p += (size_t)E * E * 2;
    u16* wo_h = (u16*)p; p += (size_t)E * E * 2;
    u16* wo_l = (u16*)p; p += (size_t)E * E * 2;
    float* q_f32 = (float*)p; p += (size_t)S * E * 4;
    float* k_f32 = (float*)p; p += (size_t)S * E * 4;
    u16* qbf = (u16*)p; p += (size_t)H * S * 96 * 2;
    u16* kbf = (u16*)p; p += (size_t)H * S * 96 * 2;
    u16* vt  = (u16*)p; p += (size_t)H * 80 * S * 2;
    // attn hi/lo alias q_f32 (dead after rope_convert)
    u16* ah = (u16*)q_f32;
    u16* al = ah + (size_t)S * E;

    convert_inputs<<<7488, 256, 0, stream>>>(hs, q_w, k_w, v_w, o_w,
                                             hs_h, wq_h, wk_h, wv_h, wo_h, wo_l);
    dim3 gq(E / 64, S / 64, 3);
    gemm_qkv<<<gq, 256, 0, stream>>>(hs_h, wq_h, wk_h, wv_h, q_b, k_b, v_b,
                                     q_f32, k_f32, vt);
    rope_convert<<<(S * H * 36) / 256, 256, 0, stream>>>(q_f32, k_f32, cosp, sinp,
                                                         qbf, kbf, vt);
    dim3 ga(S / 64, H);
    attn_mfma<<<ga, 256, 0, stream>>>(qbf, kbf, vt, ah, al, cu);
    dim3 go(E / 64, S / 64);
    gemm_o<<<go, 256, 0, stream>>>(ah, al, wo_h, wo_l, o_b, out);
}

// Round 3
// 146.593 us; speedup vs baseline: 8.4549x; 1.9131x over previous
//
#include <hip/hip_runtime.h>

#define S 2048
#define E 1152
#define H 16
#define NSEG 4

typedef unsigned short u16;
typedef short bf16x8 __attribute__((ext_vector_type(8)));
typedef float f32x4 __attribute__((ext_vector_type(4)));

#define MFMA __builtin_amdgcn_mfma_f32_16x16x32_bf16

__device__ __forceinline__ u16 f2bf(float x) {
    unsigned u = __float_as_uint(x);
    u += 0x7fffu + ((u >> 16) & 1u);
    return (u16)(u >> 16);
}
__device__ __forceinline__ float bf2f(u16 h) {
    return __uint_as_float(((unsigned)h) << 16);
}
__device__ __forceinline__ bf16x8 ldb8(const u16* p) {
    return *(const bf16x8*)p;
}
__device__ __forceinline__ void gll16(const void* g, void* s) {
    __builtin_amdgcn_global_load_lds(
        (const __attribute__((address_space(1))) void*)g,
        (__attribute__((address_space(3))) void*)s,
        16, 0, 0);
}

// ---------------- fp32 -> bf16 conversion of hs + weights ----------------
__global__ __launch_bounds__(256)
void convert_inputs(const float* __restrict__ hs, const float* __restrict__ wq,
                    const float* __restrict__ wk, const float* __restrict__ wv,
                    const float* __restrict__ wo,
                    u16* __restrict__ hs_h, u16* __restrict__ wq_h,
                    u16* __restrict__ wk_h, u16* __restrict__ wv_h,
                    u16* __restrict__ wo_h, u16* __restrict__ wo_l)
{
    const size_t NH = (size_t)S * E, NW = (size_t)E * E;
    size_t i = ((size_t)blockIdx.x * 256 + threadIdx.x) * 4;
    const float* src; u16* dst; u16* dst2 = nullptr; size_t off;
    if      (i < NH)          { src = hs; dst = hs_h; off = i; }
    else if (i < NH + NW)     { src = wq; dst = wq_h; off = i - NH; }
    else if (i < NH + 2*NW)   { src = wk; dst = wk_h; off = i - NH - NW; }
    else if (i < NH + 3*NW)   { src = wv; dst = wv_h; off = i - NH - 2*NW; }
    else if (i < NH + 4*NW)   { src = wo; dst = wo_h; dst2 = wo_l; off = i - NH - 3*NW; }
    else return;
    float4 v = *(const float4*)(src + off);
    ushort4 hv;
    hv.x = f2bf(v.x); hv.y = f2bf(v.y); hv.z = f2bf(v.z); hv.w = f2bf(v.w);
    *(ushort4*)(dst + off) = hv;
    if (dst2) {
        ushort4 lv;
        lv.x = f2bf(v.x - bf2f(hv.x)); lv.y = f2bf(v.y - bf2f(hv.y));
        lv.z = f2bf(v.z - bf2f(hv.z)); lv.w = f2bf(v.w - bf2f(hv.w));
        *(ushort4*)(dst2 + off) = lv;
    }
}

// ---------------- fused QKV projection, LDS-staged MFMA --------------------
// C[S,3456] = hs[S,1152] @ Wcat[3456,1152]^T + bias. 128x128 tile, BK=64.
// grid (27, 16); block 256 = 4 waves (2x2), wave tile 64x64.
__global__ __launch_bounds__(256)
void gemm_qkv_f(const u16* __restrict__ hsb, const u16* __restrict__ wcat,
                const float* __restrict__ qb, const float* __restrict__ kb,
                const float* __restrict__ vb,
                float* __restrict__ qo, float* __restrict__ ko, u16* __restrict__ vt)
{
    __shared__ u16 As[128 * 64] __attribute__((aligned(16)));
    __shared__ u16 Bs[128 * 64] __attribute__((aligned(16)));
    const int tid = threadIdx.x;
    const int l = tid & 63, w = tid >> 6;
    const int wr = w >> 1, wc = w & 1;
    const int m0 = blockIdx.y * 128;
    const int n0 = blockIdx.x * 128;
    const int lr = l & 15, lk = (l >> 4) * 8;

    // staging: thread t covers LDS bytes [r*4096 + t*16), row = r*32 + t/8, col = (t%8)*8
    const int srow = tid >> 3;
    const int scol = (tid & 7) * 8;
    const u16* ga = hsb  + (size_t)(m0 + srow) * E + scol;
    const u16* gb = wcat + (size_t)(n0 + srow) * E + scol;
    u16* lA = As + w * 512;   // + r*2048 per round; lane*16B implicit
    u16* lB = Bs + w * 512;

    f32x4 acc[4][4] = {};

    for (int kt = 0; kt < 18; ++kt) {
#pragma unroll
        for (int r = 0; r < 4; ++r) {
            gll16(ga + (size_t)r * 32 * E, lA + r * 2048);
            gll16(gb + (size_t)r * 32 * E, lB + r * 2048);
        }
        ga += 64; gb += 64;
        __syncthreads();
#pragma unroll
        for (int kk = 0; kk < 2; ++kk) {
            bf16x8 af[4], bf[4];
#pragma unroll
            for (int i = 0; i < 4; ++i) {
                af[i] = ldb8(As + (wr * 64 + i * 16 + lr) * 64 + kk * 32 + lk);
                bf[i] = ldb8(Bs + (wc * 64 + i * 16 + lr) * 64 + kk * 32 + lk);
            }
#pragma unroll
            for (int i = 0; i < 4; ++i)
#pragma unroll
                for (int j = 0; j < 4; ++j)
                    acc[i][j] = MFMA(af[i], bf[j], acc[i][j], 0, 0, 0);
        }
        __syncthreads();
    }

    const int zb = n0 / E;                 // 0=q, 1=k, 2=v
    const int ncol = n0 - zb * E;          // column offset within E
    const float* bias = (zb == 0) ? qb : (zb == 1) ? kb : vb;
    float* outp = (zb == 0) ? qo : ko;
#pragma unroll
    for (int i = 0; i < 4; ++i) {
        int rbase = m0 + wr * 64 + i * 16 + (l >> 4) * 4;
#pragma unroll
        for (int j = 0; j < 4; ++j) {
            int cc = ncol + wc * 64 + j * 16 + lr;
#pragma unroll
            for (int r = 0; r < 4; ++r) {
                float val = acc[i][j][r] + bias[cc];
                if (zb < 2) {
                    outp[(size_t)(rbase + r) * E + cc] = val;
                } else {
                    int hh = cc / 72, d = cc - hh * 72;
                    vt[((size_t)hh * 80 + d) * S + rbase + r] = f2bf(val);
                }
            }
        }
    }
}

// ---------------- RoPE (fp32) + pack q,k to padded bf16 + vt pad zeros -----
__global__ __launch_bounds__(256)
void rope_convert(const float* __restrict__ qf, const float* __restrict__ kf,
                  const float* __restrict__ cosp, const float* __restrict__ sinp,
                  u16* __restrict__ qbf, u16* __restrict__ kbf, u16* __restrict__ vt)
{
    int idx = blockIdx.x * 256 + threadIdx.x;
    if (idx >= S * H * 36) return;
    int d = idx % 36;
    int h = (idx / 36) % H;
    int s = idx / (36 * H);
    float c = cosp[s * 72 + d], sn = sinp[s * 72 + d];
    size_t base = (size_t)s * E + h * 72;
    float q0 = qf[base + d], q1 = qf[base + d + 36];
    float k0 = kf[base + d], k1 = kf[base + d + 36];
    const float scale = 0.1178511301977579f;  // 72^-0.5
    float rq0 = (q0 * c - q1 * sn) * scale;
    float rq1 = (q1 * c + q0 * sn) * scale;
    float rk0 = k0 * c - k1 * sn;
    float rk1 = k1 * c + k0 * sn;
    size_t qkbase = ((size_t)h * S + s) * 96;
    qbf[qkbase + d] = f2bf(rq0); qbf[qkbase + d + 36] = f2bf(rq1);
    kbf[qkbase + d] = f2bf(rk0); kbf[qkbase + d + 36] = f2bf(rk1);
    if (d < 24) { qbf[qkbase + 72 + d] = 0; kbf[qkbase + 72 + d] = 0; }
    if (d < 8)  { vt[((size_t)h * 80 + 72 + d) * S + s] = 0; }
}

// ---------------- flash attention, bf16 MFMA, barrier-free ----------------
__global__ __launch_bounds__(256)
void attn_mfma(const u16* __restrict__ qbf, const u16* __restrict__ kbf,
               const u16* __restrict__ vt, u16* __restrict__ ah, u16* __restrict__ al,
               const int* __restrict__ cu)
{
    __shared__ u16 p_lds[4][16][72] __attribute__((aligned(16)));
    const int h = blockIdx.y;
    const int q0 = blockIdx.x * 64;
    const int l = threadIdx.x & 63, w = threadIdx.x >> 6;

    int kstart = 0, kend = S;
#pragma unroll
    for (int i = 0; i < NSEG; ++i) {
        int a = cu[i], b = cu[i + 1];
        if (q0 >= a && q0 < b) { kstart = a; kend = b; }
    }

    const int koff = (l >> 4) * 8;
    const int qrow = q0 + w * 16 + (l & 15);
    bf16x8 qfr[3];
#pragma unroll
    for (int ks = 0; ks < 3; ++ks)
        qfr[ks] = ldb8(qbf + ((size_t)h * S + qrow) * 96 + ks * 32 + koff);

    f32x4 oacc[5] = {};
    float m[4], lsum[4];
#pragma unroll
    for (int r = 0; r < 4; ++r) { m[r] = -3.0e38f; lsum[r] = 0.f; }

    for (int kv0 = kstart; kv0 < kend; kv0 += 64) {
        f32x4 sc[4] = {};
#pragma unroll
        for (int nt = 0; nt < 4; ++nt) {
            const u16* kp = kbf + ((size_t)h * S + kv0 + nt * 16 + (l & 15)) * 96 + koff;
#pragma unroll
            for (int ks = 0; ks < 3; ++ks) {
                bf16x8 kfr = ldb8(kp + ks * 32);
                sc[nt] = MFMA(qfr[ks], kfr, sc[nt], 0, 0, 0);
            }
        }
        float mn[4], alpha[4];
#pragma unroll
        for (int r = 0; r < 4; ++r) {
            float mx = fmaxf(fmaxf(sc[0][r], sc[1][r]), fmaxf(sc[2][r], sc[3][r]));
            mx = fmaxf(mx, __shfl_xor(mx, 1));
            mx = fmaxf(mx, __shfl_xor(mx, 2));
            mx = fmaxf(mx, __shfl_xor(mx, 4));
            mx = fmaxf(mx, __shfl_xor(mx, 8));
            mn[r] = fmaxf(m[r], mx);
            alpha[r] = __expf(m[r] - mn[r]);
            m[r] = mn[r];
        }
        float rs[4] = {0.f, 0.f, 0.f, 0.f};
#pragma unroll
        for (int nt = 0; nt < 4; ++nt)
#pragma unroll
            for (int r = 0; r < 4; ++r) {
                float p = __expf(sc[nt][r] - mn[r]);
                rs[r] += p;
                p_lds[w][(l >> 4) * 4 + r][(l & 15) + nt * 16] = f2bf(p);
            }
#pragma unroll
        for (int r = 0; r < 4; ++r) {
            float t = rs[r];
            t += __shfl_xor(t, 1);
            t += __shfl_xor(t, 2);
            t += __shfl_xor(t, 4);
            t += __shfl_xor(t, 8);
            lsum[r] = lsum[r] * alpha[r] + t;
        }
#pragma unroll
        for (int nt = 0; nt < 5; ++nt)
#pragma unroll
            for (int r = 0; r < 4; ++r) oacc[nt][r] *= alpha[r];
#pragma unroll
        for (int ks = 0; ks < 2; ++ks) {
            bf16x8 pf = ldb8(&p_lds[w][l & 15][ks * 32 + koff]);
#pragma unroll
            for (int nt = 0; nt < 5; ++nt) {
                bf16x8 vf = ldb8(vt + ((size_t)h * 80 + nt * 16 + (l & 15)) * S + kv0 + ks * 32 + koff);
                oacc[nt] = MFMA(pf, vf, oacc[nt], 0, 0, 0);
            }
        }
    }
#pragma unroll
    for (int r = 0; r < 4; ++r) {
        float inv = 1.0f / lsum[r];
        int srow = q0 + w * 16 + (l >> 4) * 4 + r;
#pragma unroll
        for (int nt = 0; nt < 5; ++nt) {
            int d = nt * 16 + (l & 15);
            if (d < 72) {
                float val = oacc[nt][r] * inv;
                u16 hi = f2bf(val);
                u16 lo = f2bf(val - bf2f(hi));
                ah[(size_t)srow * E + h * 72 + d] = hi;
                al[(size_t)srow * E + h * 72 + d] = lo;
            }
        }
    }
}

// ---------------- O projection: split-bf16 GEMM, LDS-staged ----------------
// out[S,E] = (aH+aL)[S,E] @ (wH+wL)[E,E]^T + b, 3-term split.
// 64(M)x128(N) tile, BK=64; grid (9, 32); 4 waves (2x2), wave tile 32x64.
__global__ __launch_bounds__(256)
void gemm_o_split(const u16* __restrict__ ah, const u16* __restrict__ al,
                  const u16* __restrict__ wh, const u16* __restrict__ wl,
                  const float* __restrict__ bias, float* __restrict__ out)
{
    __shared__ u16 Ah[64 * 64]  __attribute__((aligned(16)));
    __shared__ u16 Al[64 * 64]  __attribute__((aligned(16)));
    __shared__ u16 Bh[128 * 64] __attribute__((aligned(16)));
    __shared__ u16 Bl[128 * 64] __attribute__((aligned(16)));
    const int tid = threadIdx.x;
    const int l = tid & 63, w = tid >> 6;
    const int wr = w >> 1, wc = w & 1;
    const int m0 = blockIdx.y * 64;
    const int n0 = blockIdx.x * 128;
    const int lr = l & 15, lk = (l >> 4) * 8;

    const int srow = tid >> 3;
    const int scol = (tid & 7) * 8;
    const u16* gah = ah + (size_t)(m0 + srow) * E + scol;
    const u16* gal = al + (size_t)(m0 + srow) * E + scol;
    const u16* gbh = wh + (size_t)(n0 + srow) * E + scol;
    const u16* gbl = wl + (size_t)(n0 + srow) * E + scol;
    u16* lAh = Ah + w * 512;
    u16* lAl = Al + w * 512;
    u16* lBh = Bh + w * 512;
    u16* lBl = Bl + w * 512;

    f32x4 acc[2][4] = {};

    for (int kt = 0; kt < 18; ++kt) {
#pragma unroll
        for (int r = 0; r < 2; ++r) {
            gll16(gah + (size_t)r * 32 * E, lAh + r * 2048);
            gll16(gal + (size_t)r * 32 * E, lAl + r * 2048);
        }
#pragma unroll
        for (int r = 0; r < 4; ++r) {
            gll16(gbh + (size_t)r * 32 * E, lBh + r * 2048);
            gll16(gbl + (size_t)r * 32 * E, lBl + r * 2048);
        }
        gah += 64; gal += 64; gbh += 64; gbl += 64;
        __syncthreads();
#pragma unroll
        for (int kk = 0; kk < 2; ++kk) {
            bf16x8 fah[2], fal[2], fbh[4], fbl[4];
#pragma unroll
            for (int i = 0; i < 2; ++i) {
                fah[i] = ldb8(Ah + (wr * 32 + i * 16 + lr) * 64 + kk * 32 + lk);
                fal[i] = ldb8(Al + (wr * 32 + i * 16 + lr) * 64 + kk * 32 + lk);
            }
#pragma unroll
            for (int j = 0; j < 4; ++j) {
                fbh[j] = ldb8(Bh + (wc * 64 + j * 16 + lr) * 64 + kk * 32 + lk);
                fbl[j] = ldb8(Bl + (wc * 64 + j * 16 + lr) * 64 + kk * 32 + lk);
            }
#pragma unroll
            for (int i = 0; i < 2; ++i)
#pragma unroll
                for (int j = 0; j < 4; ++j) {
                    acc[i][j] = MFMA(fah[i], fbh[j], acc[i][j], 0, 0, 0);
                    acc[i][j] = MFMA(fah[i], fbl[j], acc[i][j], 0, 0, 0);
                    acc[i][j] = MFMA(fal[i], fbh[j], acc[i][j], 0, 0, 0);
                }
        }
        __syncthreads();
    }
#pragma unroll
    for (int i = 0; i < 2; ++i) {
        int rbase = m0 + wr * 32 + i * 16 + (l >> 4) * 4;
#pragma unroll
        for (int j = 0; j < 4; ++j) {
            int cc = n0 + wc * 64 + j * 16 + lr;
#pragma unroll
            for (int r = 0; r < 4; ++r)
                out[(size_t)(rbase + r) * E + cc] = acc[i][j][r] + bias[cc];
        }
    }
}

extern "C" void kernel_launch(void* const* d_in, const int* in_sizes, int n_in,
                              void* d_out, int out_size, void* d_ws, size_t ws_size,
                              hipStream_t stream)
{
    const float* hs   = (const float*)d_in[0];
    const float* q_w  = (const float*)d_in[1];
    const float* q_b  = (const float*)d_in[2];
    const float* k_w  = (const float*)d_in[3];
    const float* k_b  = (const float*)d_in[4];
    const float* v_w  = (const float*)d_in[5];
    const float* v_b  = (const float*)d_in[6];
    const float* o_w  = (const float*)d_in[7];
    const float* o_b  = (const float*)d_in[8];
    const float* cosp = (const float*)d_in[9];
    const float* sinp = (const float*)d_in[10];
    const int*   cu   = (const int*)d_in[11];
    float* out = (float*)d_out;

    char* p = (char*)d_ws;
    u16* hs_h = (u16*)p; p += (size_t)S * E * 2;
    u16* wq_h = (u16*)p; p += (size_t)E * E * 2;   // wq/wk/wv contiguous = Wcat[3456][1152]
    u16* wk_h = (u16*)p; p += (size_t)E * E * 2;
    u16* wv_h = (u16*)p; p += (size_t)E * E * 2;
    u16* wo_h = (u16*)p; p += (size_t)E * E * 2;
    u16* wo_l = (u16*)p; p += (size_t)E * E * 2;
    float* q_f32 = (float*)p; p += (size_t)S * E * 4;
    float* k_f32 = (float*)p; p += (size_t)S * E * 4;
    u16* qbf = (u16*)p; p += (size_t)H * S * 96 * 2;
    u16* kbf = (u16*)p; p += (size_t)H * S * 96 * 2;
    u16* vt  = (u16*)p; p += (size_t)H * 80 * S * 2;
    u16* ahi = (u16*)q_f32;                 // alias: q_f32 dead after rope_convert
    u16* alo = ahi + (size_t)S * E;

    convert_inputs<<<7488, 256, 0, stream>>>(hs, q_w, k_w, v_w, o_w,
                                             hs_h, wq_h, wk_h, wv_h, wo_h, wo_l);
    dim3 gq(27, 16);
    gemm_qkv_f<<<gq, 256, 0, stream>>>(hs_h, wq_h, q_b, k_b, v_b, q_f32, k_f32, vt);
    rope_convert<<<(S * H * 36) / 256, 256, 0, stream>>>(q_f32, k_f32, cosp, sinp,
                                                         qbf, kbf, vt);
    dim3 ga(S / 64, H);
    attn_mfma<<<ga, 256, 0, stream>>>(qbf, kbf, vt, ahi, alo, cu);
    dim3 go(9, 32);
    gemm_o_split<<<go, 256, 0, stream>>>(ahi, alo, wo_h, wo_l, o_b, out);
}

// Round 4
// 133.968 us; speedup vs baseline: 9.2516x; 1.0942x over previous
//
#include <hip/hip_runtime.h>

#define S 2048
#define E 1152
#define H 16
#define NSEG 4

typedef unsigned short u16;
typedef short bf16x8 __attribute__((ext_vector_type(8)));
typedef float f32x4 __attribute__((ext_vector_type(4)));

#define MFMA __builtin_amdgcn_mfma_f32_16x16x32_bf16

__device__ __forceinline__ u16 f2bf(float x) {
    unsigned u = __float_as_uint(x);
    u += 0x7fffu + ((u >> 16) & 1u);
    return (u16)(u >> 16);
}
__device__ __forceinline__ float bf2f(u16 h) {
    return __uint_as_float(((unsigned)h) << 16);
}
__device__ __forceinline__ bf16x8 ldb8(const u16* p) {
    return *(const bf16x8*)p;
}
__device__ __forceinline__ void gll16(const void* g, void* s) {
    __builtin_amdgcn_global_load_lds(
        (const __attribute__((address_space(1))) void*)g,
        (__attribute__((address_space(3))) void*)s,
        16, 0, 0);
}

// ---------------- fp32 -> bf16 conversion of hs + weights ----------------
__global__ __launch_bounds__(256)
void convert_inputs(const float* __restrict__ hs, const float* __restrict__ wq,
                    const float* __restrict__ wk, const float* __restrict__ wv,
                    const float* __restrict__ wo,
                    u16* __restrict__ hs_h, u16* __restrict__ wq_h,
                    u16* __restrict__ wk_h, u16* __restrict__ wv_h,
                    u16* __restrict__ wo_h, u16* __restrict__ wo_l)
{
    const size_t NH = (size_t)S * E, NW = (size_t)E * E;
    size_t i = ((size_t)blockIdx.x * 256 + threadIdx.x) * 4;
    const float* src; u16* dst; u16* dst2 = nullptr; size_t off;
    if      (i < NH)          { src = hs; dst = hs_h; off = i; }
    else if (i < NH + NW)     { src = wq; dst = wq_h; off = i - NH; }
    else if (i < NH + 2*NW)   { src = wk; dst = wk_h; off = i - NH - NW; }
    else if (i < NH + 3*NW)   { src = wv; dst = wv_h; off = i - NH - 2*NW; }
    else if (i < NH + 4*NW)   { src = wo; dst = wo_h; dst2 = wo_l; off = i - NH - 3*NW; }
    else return;
    float4 v = *(const float4*)(src + off);
    ushort4 hv;
    hv.x = f2bf(v.x); hv.y = f2bf(v.y); hv.z = f2bf(v.z); hv.w = f2bf(v.w);
    *(ushort4*)(dst + off) = hv;
    if (dst2) {
        ushort4 lv;
        lv.x = f2bf(v.x - bf2f(hv.x)); lv.y = f2bf(v.y - bf2f(hv.y));
        lv.z = f2bf(v.z - bf2f(hv.z)); lv.w = f2bf(v.w - bf2f(hv.w));
        *(ushort4*)(dst2 + off) = lv;
    }
}

// ---------------- fused QKV projection, LDS-staged MFMA --------------------
__global__ __launch_bounds__(256)
void gemm_qkv_f(const u16* __restrict__ hsb, const u16* __restrict__ wcat,
                const float* __restrict__ qb, const float* __restrict__ kb,
                const float* __restrict__ vb,
                float* __restrict__ qo, float* __restrict__ ko, u16* __restrict__ vt)
{
    __shared__ u16 As[128 * 64] __attribute__((aligned(16)));
    __shared__ u16 Bs[128 * 64] __attribute__((aligned(16)));
    const int tid = threadIdx.x;
    const int l = tid & 63, w = tid >> 6;
    const int wr = w >> 1, wc = w & 1;
    const int m0 = blockIdx.y * 128;
    const int n0 = blockIdx.x * 128;
    const int lr = l & 15, lk = (l >> 4) * 8;

    const int srow = tid >> 3;
    const int scol = (tid & 7) * 8;
    const u16* ga = hsb  + (size_t)(m0 + srow) * E + scol;
    const u16* gb = wcat + (size_t)(n0 + srow) * E + scol;
    u16* lA = As + w * 512;
    u16* lB = Bs + w * 512;

    f32x4 acc[4][4] = {};

    for (int kt = 0; kt < 18; ++kt) {
#pragma unroll
        for (int r = 0; r < 4; ++r) {
            gll16(ga + (size_t)r * 32 * E, lA + r * 2048);
            gll16(gb + (size_t)r * 32 * E, lB + r * 2048);
        }
        ga += 64; gb += 64;
        __syncthreads();
#pragma unroll
        for (int kk = 0; kk < 2; ++kk) {
            bf16x8 af[4], bf[4];
#pragma unroll
            for (int i = 0; i < 4; ++i) {
                af[i] = ldb8(As + (wr * 64 + i * 16 + lr) * 64 + kk * 32 + lk);
                bf[i] = ldb8(Bs + (wc * 64 + i * 16 + lr) * 64 + kk * 32 + lk);
            }
#pragma unroll
            for (int i = 0; i < 4; ++i)
#pragma unroll
                for (int j = 0; j < 4; ++j)
                    acc[i][j] = MFMA(af[i], bf[j], acc[i][j], 0, 0, 0);
        }
        __syncthreads();
    }

    const int zb = n0 / E;
    const int ncol = n0 - zb * E;
    const float* bias = (zb == 0) ? qb : (zb == 1) ? kb : vb;
    float* outp = (zb == 0) ? qo : ko;
#pragma unroll
    for (int i = 0; i < 4; ++i) {
        int rbase = m0 + wr * 64 + i * 16 + (l >> 4) * 4;
#pragma unroll
        for (int j = 0; j < 4; ++j) {
            int cc = ncol + wc * 64 + j * 16 + lr;
#pragma unroll
            for (int r = 0; r < 4; ++r) {
                float val = acc[i][j][r] + bias[cc];
                if (zb < 2) {
                    outp[(size_t)(rbase + r) * E + cc] = val;
                } else {
                    int hh = cc / 72, d = cc - hh * 72;
                    vt[((size_t)hh * 80 + d) * S + rbase + r] = f2bf(val);
                }
            }
        }
    }
}

// ---------------- RoPE (fp32) + pack q,k to padded bf16 + vt pad zeros -----
__global__ __launch_bounds__(256)
void rope_convert(const float* __restrict__ qf, const float* __restrict__ kf,
                  const float* __restrict__ cosp, const float* __restrict__ sinp,
                  u16* __restrict__ qbf, u16* __restrict__ kbf, u16* __restrict__ vt)
{
    int idx = blockIdx.x * 256 + threadIdx.x;
    if (idx >= S * H * 36) return;
    int d = idx % 36;
    int h = (idx / 36) % H;
    int s = idx / (36 * H);
    float c = cosp[s * 72 + d], sn = sinp[s * 72 + d];
    size_t base = (size_t)s * E + h * 72;
    float q0 = qf[base + d], q1 = qf[base + d + 36];
    float k0 = kf[base + d], k1 = kf[base + d + 36];
    const float scale = 0.1178511301977579f;  // 72^-0.5
    float rq0 = (q0 * c - q1 * sn) * scale;
    float rq1 = (q1 * c + q0 * sn) * scale;
    float rk0 = k0 * c - k1 * sn;
    float rk1 = k1 * c + k0 * sn;
    size_t qkbase = ((size_t)h * S + s) * 96;
    qbf[qkbase + d] = f2bf(rq0); qbf[qkbase + d + 36] = f2bf(rq1);
    kbf[qkbase + d] = f2bf(rk0); kbf[qkbase + d + 36] = f2bf(rk1);
    if (d < 24) { qbf[qkbase + 72 + d] = 0; kbf[qkbase + 72 + d] = 0; }
    if (d < 8)  { vt[((size_t)h * 80 + 72 + d) * S + s] = 0; }
}

// ---------------- flash attention helpers ---------------------------------
__device__ __forceinline__ void loadK(bf16x8 (&kf)[12], const u16* kp) {
#pragma unroll
    for (int nt = 0; nt < 4; ++nt)
#pragma unroll
        for (int ks = 0; ks < 3; ++ks)
            kf[nt * 3 + ks] = ldb8(kp + nt * 16 * 96 + ks * 32);
}
__device__ __forceinline__ void loadV(bf16x8 (&vf)[10], const u16* vp) {
#pragma unroll
    for (int nt = 0; nt < 5; ++nt)
#pragma unroll
        for (int ks = 0; ks < 2; ++ks)
            vf[nt * 2 + ks] = ldb8(vp + (size_t)nt * 16 * S + ks * 32);
}
__device__ __forceinline__ void qkStep(f32x4 (&sc)[4], const bf16x8 (&qfr)[3],
                                       const bf16x8 (&kf)[12]) {
#pragma unroll
    for (int nt = 0; nt < 4; ++nt) {
        sc[nt] = f32x4{0.f, 0.f, 0.f, 0.f};
#pragma unroll
        for (int ks = 0; ks < 3; ++ks)
            sc[nt] = MFMA(qfr[ks], kf[nt * 3 + ks], sc[nt], 0, 0, 0);
    }
}
// exp (fixed base) + P->LDS + PV accumulate
__device__ __forceinline__ void pvBody(const f32x4 (&sc)[4], float (&lsum)[4],
                                       const bf16x8 (&vf)[10], f32x4 (&oacc)[5],
                                       u16 (*pl)[72], int l) {
    const int lr = l & 15, g = l >> 4;
#pragma unroll
    for (int nt = 0; nt < 4; ++nt)
#pragma unroll
        for (int r = 0; r < 4; ++r) {
            float p = __expf(sc[nt][r]);
            lsum[r] += p;
            pl[g * 4 + r][lr + nt * 16] = f2bf(p);
        }
    const int koff = g * 8;
#pragma unroll
    for (int ks = 0; ks < 2; ++ks) {
        bf16x8 pf = ldb8(&pl[lr][ks * 32 + koff]);
#pragma unroll
        for (int nt = 0; nt < 5; ++nt)
            oacc[nt] = MFMA(pf, vf[nt * 2 + ks], oacc[nt], 0, 0, 0);
    }
}

// ---------------- flash attention, bf16 MFMA, barrier-free ----------------
// 1-D grid of 512 blocks, XCD-chunked so each XCD owns 2 complete heads.
// block = 4 waves; wave owns 16 q rows; kv chunks of 64, K double-buffered.
__global__ __launch_bounds__(256, 2)
void attn_mfma(const u16* __restrict__ qbf, const u16* __restrict__ kbf,
               const u16* __restrict__ vt, u16* __restrict__ ah, u16* __restrict__ al,
               const int* __restrict__ cu)
{
    __shared__ u16 p_lds[4][16][72] __attribute__((aligned(16)));
    const int b = blockIdx.x;
    const int sid = (b & 7) * 64 + (b >> 3);   // XCD-chunked swizzle (512 % 8 == 0)
    const int h = sid >> 5;
    const int q0 = (sid & 31) * 64;
    const int l = threadIdx.x & 63, w = threadIdx.x >> 6;

    int kstart = 0, kend = S;
#pragma unroll
    for (int i = 0; i < NSEG; ++i) {
        int a = cu[i], b2 = cu[i + 1];
        if (q0 >= a && q0 < b2) { kstart = a; kend = b2; }
    }

    const int lr = l & 15;
    const int koff = (l >> 4) * 8;
    const u16* kbase = kbf + ((size_t)h * S + lr) * 96 + koff;
    const u16* vbase = vt + ((size_t)h * 80 + lr) * S + koff;

    bf16x8 qfr[3];
#pragma unroll
    for (int ks = 0; ks < 3; ++ks)
        qfr[ks] = ldb8(qbf + ((size_t)h * S + q0 + w * 16 + lr) * 96 + ks * 32 + koff);

    f32x4 oacc[5] = {};
    float lsum[4] = {0.f, 0.f, 0.f, 0.f};

    bf16x8 kfA[12], kfB[12], vf[10];
    loadK(kfA, kbase + (size_t)kstart * 96);

    const int nch = (kend - kstart) >> 6;
    for (int c = 0; c < nch; c += 2) {
        const int kv0 = kstart + c * 64;
        // chunk c: consumes kfA, prefetches kfB
        loadV(vf, vbase + kv0);
        f32x4 sc[4];
        qkStep(sc, qfr, kfA);
        if (c + 1 < nch) loadK(kfB, kbase + (size_t)(kv0 + 64) * 96);
        pvBody(sc, lsum, vf, oacc, p_lds[w], l);
        // chunk c+1: consumes kfB, prefetches kfA
        if (c + 1 < nch) {
            loadV(vf, vbase + kv0 + 64);
            qkStep(sc, qfr, kfB);
            if (c + 2 < nch) loadK(kfA, kbase + (size_t)(kv0 + 128) * 96);
            pvBody(sc, lsum, vf, oacc, p_lds[w], l);
        }
    }

    // epilogue: row-sum reduce (16-lane), normalize, write hi/lo bf16
#pragma unroll
    for (int r = 0; r < 4; ++r) {
        float t = lsum[r];
        t += __shfl_xor(t, 1);
        t += __shfl_xor(t, 2);
        t += __shfl_xor(t, 4);
        t += __shfl_xor(t, 8);
        float inv = 1.0f / t;
        int srow = q0 + w * 16 + (l >> 4) * 4 + r;
#pragma unroll
        for (int nt = 0; nt < 5; ++nt) {
            int d = nt * 16 + lr;
            if (d < 72) {
                float val = oacc[nt][r] * inv;
                u16 hi = f2bf(val);
                u16 lo = f2bf(val - bf2f(hi));
                ah[(size_t)srow * E + h * 72 + d] = hi;
                al[(size_t)srow * E + h * 72 + d] = lo;
            }
        }
    }
}

// ---------------- O projection: split-bf16 GEMM, LDS-staged ----------------
__global__ __launch_bounds__(256)
void gemm_o_split(const u16* __restrict__ ah, const u16* __restrict__ al,
                  const u16* __restrict__ wh, const u16* __restrict__ wl,
                  const float* __restrict__ bias, float* __restrict__ out)
{
    __shared__ u16 Ah[64 * 64]  __attribute__((aligned(16)));
    __shared__ u16 Al[64 * 64]  __attribute__((aligned(16)));
    __shared__ u16 Bh[128 * 64] __attribute__((aligned(16)));
    __shared__ u16 Bl[128 * 64] __attribute__((aligned(16)));
    const int tid = threadIdx.x;
    const int l = tid & 63, w = tid >> 6;
    const int wr = w >> 1, wc = w & 1;
    const int m0 = blockIdx.y * 64;
    const int n0 = blockIdx.x * 128;
    const int lr = l & 15, lk = (l >> 4) * 8;

    const int srow = tid >> 3;
    const int scol = (tid & 7) * 8;
    const u16* gah = ah + (size_t)(m0 + srow) * E + scol;
    const u16* gal = al + (size_t)(m0 + srow) * E + scol;
    const u16* gbh = wh + (size_t)(n0 + srow) * E + scol;
    const u16* gbl = wl + (size_t)(n0 + srow) * E + scol;
    u16* lAh = Ah + w * 512;
    u16* lAl = Al + w * 512;
    u16* lBh = Bh + w * 512;
    u16* lBl = Bl + w * 512;

    f32x4 acc[2][4] = {};

    for (int kt = 0; kt < 18; ++kt) {
#pragma unroll
        for (int r = 0; r < 2; ++r) {
            gll16(gah + (size_t)r * 32 * E, lAh + r * 2048);
            gll16(gal + (size_t)r * 32 * E, lAl + r * 2048);
        }
#pragma unroll
        for (int r = 0; r < 4; ++r) {
            gll16(gbh + (size_t)r * 32 * E, lBh + r * 2048);
            gll16(gbl + (size_t)r * 32 * E, lBl + r * 2048);
        }
        gah += 64; gal += 64; gbh += 64; gbl += 64;
        __syncthreads();
#pragma unroll
        for (int kk = 0; kk < 2; ++kk) {
            bf16x8 fah[2], fal[2], fbh[4], fbl[4];
#pragma unroll
            for (int i = 0; i < 2; ++i) {
                fah[i] = ldb8(Ah + (wr * 32 + i * 16 + lr) * 64 + kk * 32 + lk);
                fal[i] = ldb8(Al + (wr * 32 + i * 16 + lr) * 64 + kk * 32 + lk);
            }
#pragma unroll
            for (int j = 0; j < 4; ++j) {
                fbh[j] = ldb8(Bh + (wc * 64 + j * 16 + lr) * 64 + kk * 32 + lk);
                fbl[j] = ldb8(Bl + (wc * 64 + j * 16 + lr) * 64 + kk * 32 + lk);
            }
#pragma unroll
            for (int i = 0; i < 2; ++i)
#pragma unroll
                for (int j = 0; j < 4; ++j) {
                    acc[i][j] = MFMA(fah[i], fbh[j], acc[i][j], 0, 0, 0);
                    acc[i][j] = MFMA(fah[i], fbl[j], acc[i][j], 0, 0, 0);
                    acc[i][j] = MFMA(fal[i], fbh[j], acc[i][j], 0, 0, 0);
                }
        }
        __syncthreads();
    }
#pragma unroll
    for (int i = 0; i < 2; ++i) {
        int rbase = m0 + wr * 32 + i * 16 + (l >> 4) * 4;
#pragma unroll
        for (int j = 0; j < 4; ++j) {
            int cc = n0 + wc * 64 + j * 16 + lr;
#pragma unroll
            for (int r = 0; r < 4; ++r)
                out[(size_t)(rbase + r) * E + cc] = acc[i][j][r] + bias[cc];
        }
    }
}

extern "C" void kernel_launch(void* const* d_in, const int* in_sizes, int n_in,
                              void* d_out, int out_size, void* d_ws, size_t ws_size,
                              hipStream_t stream)
{
    const float* hs   = (const float*)d_in[0];
    const float* q_w  = (const float*)d_in[1];
    const float* q_b  = (const float*)d_in[2];
    const float* k_w  = (const float*)d_in[3];
    const float* k_b  = (const float*)d_in[4];
    const float* v_w  = (const float*)d_in[5];
    const float* v_b  = (const float*)d_in[6];
    const float* o_w  = (const float*)d_in[7];
    const float* o_b  = (const float*)d_in[8];
    const float* cosp = (const float*)d_in[9];
    const float* sinp = (const float*)d_in[10];
    const int*   cu   = (const int*)d_in[11];
    float* out = (float*)d_out;

    char* p = (char*)d_ws;
    u16* hs_h = (u16*)p; p += (size_t)S * E * 2;
    u16* wq_h = (u16*)p; p += (size_t)E * E * 2;   // wq/wk/wv contiguous = Wcat[3456][1152]
    u16* wk_h = (u16*)p; p += (size_t)E * E * 2;
    u16* wv_h = (u16*)p; p += (size_t)E * E * 2;
    u16* wo_h = (u16*)p; p += (size_t)E * E * 2;
    u16* wo_l = (u16*)p; p += (size_t)E * E * 2;
    float* q_f32 = (float*)p; p += (size_t)S * E * 4;
    float* k_f32 = (float*)p; p += (size_t)S * E * 4;
    u16* qbf = (u16*)p; p += (size_t)H * S * 96 * 2;
    u16* kbf = (u16*)p; p += (size_t)H * S * 96 * 2;
    u16* vt  = (u16*)p; p += (size_t)H * 80 * S * 2;
    u16* ahi = (u16*)q_f32;                 // alias: q_f32 dead after rope_convert
    u16* alo = ahi + (size_t)S * E;

    convert_inputs<<<7488, 256, 0, stream>>>(hs, q_w, k_w, v_w, o_w,
                                             hs_h, wq_h, wk_h, wv_h, wo_h, wo_l);
    dim3 gq(27, 16);
    gemm_qkv_f<<<gq, 256, 0, stream>>>(hs_h, wq_h, q_b, k_b, v_b, q_f32, k_f32, vt);
    rope_convert<<<(S * H * 36) / 256, 256, 0, stream>>>(q_f32, k_f32, cosp, sinp,
                                                         qbf, kbf, vt);
    attn_mfma<<<512, 256, 0, stream>>>(qbf, kbf, vt, ahi, alo, cu);
    dim3 go(9, 32);
    gemm_o_split<<<go, 256, 0, stream>>>(ahi, alo, wo_h, wo_l, o_b, out);
}